// Round 1
// baseline (850.774 us; speedup 1.0000x reference)
//
#include <hip/hip_runtime.h>
#include <stdint.h>

#define T_TOK 8192
#define DIM   1024
#define HID   2048
#define NE    8

#define BM 128
#define BN 128
#define BK 64
#define LDK 72   // padded LDS k-stride (bf16 elems): 64+8 -> rows offset by 144B

typedef float floatx4 __attribute__((ext_vector_type(4)));
typedef short shortx8 __attribute__((ext_vector_type(8)));

__device__ __forceinline__ unsigned short f2bf(float f) {
  unsigned int u = __float_as_uint(f);
  unsigned int r = 0x7fffu + ((u >> 16) & 1u);
  return (unsigned short)((u + r) >> 16);
}

// ---------------- cast x f32 -> bf16 ----------------
__global__ __launch_bounds__(256) void cast_x_kernel(const float* __restrict__ x,
                                                     unsigned short* __restrict__ xb) {
  size_t i = ((size_t)blockIdx.x * 256 + threadIdx.x) * 4;
  float4 v = *reinterpret_cast<const float4*>(x + i);
  ushort4 o;
  o.x = f2bf(v.x); o.y = f2bf(v.y); o.z = f2bf(v.z); o.w = f2bf(v.w);
  *reinterpret_cast<ushort4*>(xb + i) = o;
}

// ------------- transpose+cast: in [R][C] f32 -> out [C][R] bf16, blockIdx.z = expert -------------
__global__ __launch_bounds__(256) void transpose_cast_kernel(const float* __restrict__ in,
                                                             unsigned short* __restrict__ out,
                                                             int R, int C) {
  __shared__ float tile[32][33];
  const size_t eoff = (size_t)blockIdx.z * R * C;
  const float* ip = in + eoff;
  unsigned short* op = out + eoff;
  int c0 = blockIdx.x * 32, r0 = blockIdx.y * 32;
  int tx = threadIdx.x, ty = threadIdx.y;
#pragma unroll
  for (int i = 0; i < 4; i++)
    tile[ty + i * 8][tx] = ip[(size_t)(r0 + ty + i * 8) * C + (c0 + tx)];
  __syncthreads();
#pragma unroll
  for (int i = 0; i < 4; i++)
    op[(size_t)(c0 + ty + i * 8) * R + (r0 + tx)] = f2bf(tile[tx][ty + i * 8]);
}

// ---------------- gating: one wave per token ----------------
__global__ __launch_bounds__(256) void gate_kernel(const float* __restrict__ x,
                                                   const float* __restrict__ wg,
                                                   int* counts, int* top1cnt, float* ssum,
                                                   int* tok_list, float* wgt_list) {
  __shared__ float bs[4][8];
  int wave = threadIdx.x >> 6;
  int lane = threadIdx.x & 63;
  int t = blockIdx.x * 4 + wave;

  float acc[8];
#pragma unroll
  for (int e = 0; e < 8; e++) acc[e] = 0.f;
  const float* xr = x + (size_t)t * DIM;
#pragma unroll
  for (int i = 0; i < 16; i++) {
    int d = i * 64 + lane;
    float xv = xr[d];
    const float4* wr = reinterpret_cast<const float4*>(wg + d * 8);
    float4 w0 = wr[0], w1 = wr[1];
    acc[0] += xv * w0.x; acc[1] += xv * w0.y; acc[2] += xv * w0.z; acc[3] += xv * w0.w;
    acc[4] += xv * w1.x; acc[5] += xv * w1.y; acc[6] += xv * w1.z; acc[7] += xv * w1.w;
  }
#pragma unroll
  for (int e = 0; e < 8; e++) {
#pragma unroll
    for (int off = 32; off > 0; off >>= 1) acc[e] += __shfl_xor(acc[e], off, 64);
  }
  if (lane == 0) {
    float mx = acc[0];
#pragma unroll
    for (int e = 1; e < 8; e++) mx = fmaxf(mx, acc[e]);
    float s[8], sum = 0.f;
#pragma unroll
    for (int e = 0; e < 8; e++) { s[e] = expf(acc[e] - mx); sum += s[e]; }
    float inv = 1.f / sum;
#pragma unroll
    for (int e = 0; e < 8; e++) { s[e] *= inv; bs[wave][e] = s[e]; }
    // top-2 (strict > : ties -> lower index, matches lax.top_k)
    int i1 = 0;
#pragma unroll
    for (int e = 1; e < 8; e++) if (s[e] > s[i1]) i1 = e;
    int i2 = (i1 == 0) ? 1 : 0;
#pragma unroll
    for (int e = 0; e < 8; e++) if (e != i1 && s[e] > s[i2]) i2 = e;
    atomicAdd(&top1cnt[i1], 1);
    int p1 = atomicAdd(&counts[i1], 1);
    tok_list[i1 * T_TOK + p1] = t;
    wgt_list[i1 * T_TOK + p1] = s[i1];
    int p2 = atomicAdd(&counts[i2], 1);
    tok_list[i2 * T_TOK + p2] = t;
    wgt_list[i2 * T_TOK + p2] = s[i2];
  }
  __syncthreads();
  if (threadIdx.x < 8) {
    float v = bs[0][threadIdx.x] + bs[1][threadIdx.x] + bs[2][threadIdx.x] + bs[3][threadIdx.x];
    atomicAdd(&ssum[threadIdx.x], v);
  }
}

// ---------------- scan + l_aux ----------------
__global__ void scan_kernel(const int* counts, const int* top1cnt, const float* ssum,
                            int* h_off, float* laux_out) {
  if (threadIdx.x == 0 && blockIdx.x == 0) {
    int off = 0;
    float l = 0.f;
    for (int e = 0; e < 8; e++) {
      h_off[e] = off;
      off += counts[e];
      l += (ssum[e] / (float)T_TOK) * ((float)top1cnt[e] / (float)T_TOK);
    }
    *laux_out = l * (float)NE;
  }
}

// ---------------- grouped GEMM: C = gatherA(M x K) * B^T-layout(N x K) ----------------
// MODE 0: A = x_bf gathered via tok_list; epilogue relu(acc + b1) -> h_buf bf16 (stride N==HID)
// MODE 1: A = h_buf rows (h_off[e]+row);   epilogue atomicAdd(out[tok], w*(acc + b2))
template <int MODE>
__global__ __launch_bounds__(256, 2) void moe_gemm_kernel(
    const unsigned short* __restrict__ A_src, const unsigned short* __restrict__ B_src,
    const float* __restrict__ bias, const int* __restrict__ counts,
    const int* __restrict__ h_off, const int* __restrict__ tok_list,
    const float* __restrict__ wgt_list, unsigned short* __restrict__ h_out,
    float* __restrict__ out, int N, int K) {
  __shared__ unsigned short s_a[BM][LDK];
  __shared__ unsigned short s_b[BN][LDK];

  const int e = blockIdx.z;
  const int n_e = counts[e];
  const int m0 = blockIdx.y * BM;
  if (m0 >= n_e) return;
  const int n0 = blockIdx.x * BN;
  const int tid = threadIdx.x;

  // staging assignments: chunk = it*256+tid; row = chunk>>3 (0..127), kc = tid&7
  const int kc = tid & 7;
  const unsigned short* a_ptr[4];
  const unsigned short* b_ptr[4];
  bool a_ok[4];
#pragma unroll
  for (int it = 0; it < 4; it++) {
    int row = it * 32 + (tid >> 3);
    int gr = m0 + row;
    a_ok[it] = (gr < n_e);
    int safe = a_ok[it] ? gr : 0;
    if (MODE == 0) {
      int tok = tok_list[e * T_TOK + safe];
      a_ptr[it] = A_src + (size_t)tok * K;
    } else {
      a_ptr[it] = A_src + (size_t)(h_off[e] + safe) * K;
    }
    b_ptr[it] = B_src + ((size_t)e * N + n0 + row) * K;
  }

  const int lane = tid & 63;
  const int wv = tid >> 6;
  const int wm = (wv >> 1) * 64;
  const int wn = (wv & 1) * 64;
  const int lm = lane & 15;
  const int quad = lane >> 4;

  floatx4 acc[4][4];
#pragma unroll
  for (int mi = 0; mi < 4; mi++)
#pragma unroll
    for (int ni = 0; ni < 4; ni++) acc[mi][ni] = (floatx4){0.f, 0.f, 0.f, 0.f};

  for (int kt = 0; kt < K; kt += BK) {
#pragma unroll
    for (int it = 0; it < 4; it++) {
      int row = it * 32 + (tid >> 3);
      uint4 va = {0u, 0u, 0u, 0u};
      if (a_ok[it]) va = *reinterpret_cast<const uint4*>(a_ptr[it] + kt + kc * 8);
      *reinterpret_cast<uint4*>(&s_a[row][kc * 8]) = va;
      uint4 vb = *reinterpret_cast<const uint4*>(b_ptr[it] + kt + kc * 8);
      *reinterpret_cast<uint4*>(&s_b[row][kc * 8]) = vb;
    }
    __syncthreads();
#pragma unroll
    for (int kk = 0; kk < 2; kk++) {
      shortx8 af[4], bfr[4];
#pragma unroll
      for (int mi = 0; mi < 4; mi++)
        af[mi] = *reinterpret_cast<const shortx8*>(&s_a[wm + mi * 16 + lm][kk * 32 + quad * 8]);
#pragma unroll
      for (int ni = 0; ni < 4; ni++)
        bfr[ni] = *reinterpret_cast<const shortx8*>(&s_b[wn + ni * 16 + lm][kk * 32 + quad * 8]);
#pragma unroll
      for (int mi = 0; mi < 4; mi++)
#pragma unroll
        for (int ni = 0; ni < 4; ni++)
          acc[mi][ni] = __builtin_amdgcn_mfma_f32_16x16x32_bf16(af[mi], bfr[ni], acc[mi][ni], 0, 0, 0);
    }
    __syncthreads();
  }

  // epilogue: D row = quad*4 + r, col = lm (verified C/D layout)
#pragma unroll
  for (int mi = 0; mi < 4; mi++) {
#pragma unroll
    for (int r = 0; r < 4; r++) {
      int row = m0 + wm + mi * 16 + quad * 4 + r;
      if (row >= n_e) continue;
      if (MODE == 0) {
        size_t base = (size_t)(h_off[e] + row) * N;
#pragma unroll
        for (int ni = 0; ni < 4; ni++) {
          int col = n0 + wn + ni * 16 + lm;
          float v = acc[mi][ni][r] + bias[e * N + col];
          v = fmaxf(v, 0.f);
          h_out[base + col] = f2bf(v);
        }
      } else {
        int tok = tok_list[e * T_TOK + row];
        float wgt = wgt_list[e * T_TOK + row];
        size_t base = (size_t)tok * N;
#pragma unroll
        for (int ni = 0; ni < 4; ni++) {
          int col = n0 + wn + ni * 16 + lm;
          float v = wgt * (acc[mi][ni][r] + bias[e * N + col]);
          atomicAdd(&out[base + col], v);
        }
      }
    }
  }
}

extern "C" void kernel_launch(void* const* d_in, const int* in_sizes, int n_in,
                              void* d_out, int out_size, void* d_ws, size_t ws_size,
                              hipStream_t stream) {
  const float* x  = (const float*)d_in[0];
  const float* wg = (const float*)d_in[1];
  const float* w1 = (const float*)d_in[2];
  const float* b1 = (const float*)d_in[3];
  const float* w2 = (const float*)d_in[4];
  const float* b2 = (const float*)d_in[5];
  float* out = (float*)d_out;

  char* ws = (char*)d_ws;
  // ws layout (bytes), all 256-aligned; total ~151.5 MB
  int*            counts   = (int*)(ws + 0);
  int*            top1cnt  = (int*)(ws + 32);
  float*          ssum     = (float*)(ws + 64);
  int*            h_off    = (int*)(ws + 96);
  int*            tok_list = (int*)(ws + 256);
  float*          wgt_list = (float*)(ws + 262400);
  unsigned short* x_bf     = (unsigned short*)(ws + 524544);
  unsigned short* w1t      = (unsigned short*)(ws + 17301760);
  unsigned short* w2t      = (unsigned short*)(ws + 50856192);
  unsigned short* h_buf    = (unsigned short*)(ws + 84410624);

  hipMemsetAsync(ws, 0, 256, stream);
  hipMemsetAsync(d_out, 0, (size_t)out_size * sizeof(float), stream);

  cast_x_kernel<<<(T_TOK * DIM) / 1024, 256, 0, stream>>>(x, x_bf);

  dim3 tb(32, 8);
  transpose_cast_kernel<<<dim3(HID / 32, DIM / 32, NE), tb, 0, stream>>>(w1, w1t, DIM, HID);
  transpose_cast_kernel<<<dim3(DIM / 32, HID / 32, NE), tb, 0, stream>>>(w2, w2t, HID, DIM);

  gate_kernel<<<T_TOK / 4, 256, 0, stream>>>(x, wg, counts, top1cnt, ssum, tok_list, wgt_list);
  scan_kernel<<<1, 64, 0, stream>>>(counts, top1cnt, ssum, h_off, out + (size_t)T_TOK * DIM);

  // GEMM1: M=n_e, N=HID, K=DIM
  moe_gemm_kernel<0><<<dim3(HID / BN, T_TOK / BM, NE), 256, 0, stream>>>(
      x_bf, w1t, b1, counts, h_off, tok_list, wgt_list, h_buf, nullptr, HID, DIM);
  // GEMM2: M=n_e, N=DIM, K=HID
  moe_gemm_kernel<1><<<dim3(DIM / BN, T_TOK / BM, NE), 256, 0, stream>>>(
      h_buf, w2t, b2, counts, h_off, tok_list, wgt_list, nullptr, out, DIM, HID);
}

// Round 2
// 585.660 us; speedup vs baseline: 1.4527x; 1.4527x over previous
//
#include <hip/hip_runtime.h>
#include <stdint.h>

#define T_TOK 8192
#define DIM   1024
#define HID   2048
#define NE    8

#define BM 128
#define BN 128
#define BK 64
#define LDK 72   // padded LDS k-stride (bf16 elems): 64+8 -> rows offset by 144B

#define GB_TOK 32  // tokens per gate block

typedef float floatx4 __attribute__((ext_vector_type(4)));
typedef short shortx8 __attribute__((ext_vector_type(8)));

__device__ __forceinline__ unsigned short f2bf(float f) {
  unsigned int u = __float_as_uint(f);
  unsigned int r = 0x7fffu + ((u >> 16) & 1u);
  return (unsigned short)((u + r) >> 16);
}

// ---------------- cast x f32 -> bf16 ----------------
__global__ __launch_bounds__(256) void cast_x_kernel(const float* __restrict__ x,
                                                     unsigned short* __restrict__ xb) {
  size_t i = ((size_t)blockIdx.x * 256 + threadIdx.x) * 4;
  float4 v = *reinterpret_cast<const float4*>(x + i);
  ushort4 o;
  o.x = f2bf(v.x); o.y = f2bf(v.y); o.z = f2bf(v.z); o.w = f2bf(v.w);
  *reinterpret_cast<ushort4*>(xb + i) = o;
}

// ------------- transpose+cast: in [R][C] f32 -> out [C][R] bf16, blockIdx.z = expert -------------
__global__ __launch_bounds__(256) void transpose_cast_kernel(const float* __restrict__ in,
                                                             unsigned short* __restrict__ out,
                                                             int R, int C) {
  __shared__ float tile[32][33];
  const size_t eoff = (size_t)blockIdx.z * R * C;
  const float* ip = in + eoff;
  unsigned short* op = out + eoff;
  int c0 = blockIdx.x * 32, r0 = blockIdx.y * 32;
  int tx = threadIdx.x, ty = threadIdx.y;
#pragma unroll
  for (int i = 0; i < 4; i++)
    tile[ty + i * 8][tx] = ip[(size_t)(r0 + ty + i * 8) * C + (c0 + tx)];
  __syncthreads();
#pragma unroll
  for (int i = 0; i < 4; i++)
    op[(size_t)(c0 + ty + i * 8) * R + (r0 + tx)] = f2bf(tile[tx][ty + i * 8]);
}

// ---------------- gating: 32 tokens/block, hierarchical binning ----------------
__global__ __launch_bounds__(256) void gate_kernel(const float* __restrict__ x,
                                                   const float* __restrict__ wg,
                                                   int* counts, int* top1cnt, float* ssum,
                                                   int* tok_list, float* wgt_list) {
  __shared__ int   lds_cnt[8];
  __shared__ int   lds_top1[8];
  __shared__ float lds_ssum[4][8];
  __shared__ int   tk_e[GB_TOK][2];
  __shared__ int   tk_r[GB_TOK][2];
  __shared__ float tk_w[GB_TOK][2];
  __shared__ int   base[8];

  const int tid = threadIdx.x;
  const int wave = tid >> 6;
  const int lane = tid & 63;

  if (tid < 8) { lds_cnt[tid] = 0; lds_top1[tid] = 0; }
  if (tid < 32) lds_ssum[tid >> 3][tid & 7] = 0.f;
  __syncthreads();

  float ssum_local[8];
#pragma unroll
  for (int e = 0; e < 8; e++) ssum_local[e] = 0.f;

  for (int it = 0; it < GB_TOK / 4; it++) {
    const int lt = it * 4 + wave;
    const int t = blockIdx.x * GB_TOK + lt;

    float acc[8];
#pragma unroll
    for (int e = 0; e < 8; e++) acc[e] = 0.f;
    const float* xr = x + (size_t)t * DIM;
#pragma unroll
    for (int i = 0; i < 16; i++) {
      int d = i * 64 + lane;
      float xv = xr[d];
      const float4* wr = reinterpret_cast<const float4*>(wg + d * 8);
      float4 w0 = wr[0], w1 = wr[1];
      acc[0] += xv * w0.x; acc[1] += xv * w0.y; acc[2] += xv * w0.z; acc[3] += xv * w0.w;
      acc[4] += xv * w1.x; acc[5] += xv * w1.y; acc[6] += xv * w1.z; acc[7] += xv * w1.w;
    }
#pragma unroll
    for (int e = 0; e < 8; e++) {
#pragma unroll
      for (int off = 32; off > 0; off >>= 1) acc[e] += __shfl_xor(acc[e], off, 64);
    }
    if (lane == 0) {
      float mx = acc[0];
#pragma unroll
      for (int e = 1; e < 8; e++) mx = fmaxf(mx, acc[e]);
      float s[8], sum = 0.f;
#pragma unroll
      for (int e = 0; e < 8; e++) { s[e] = expf(acc[e] - mx); sum += s[e]; }
      float inv = 1.f / sum;
#pragma unroll
      for (int e = 0; e < 8; e++) { s[e] *= inv; ssum_local[e] += s[e]; }
      // top-2 (strict > : ties -> lower index, matches lax.top_k)
      int i1 = 0;
#pragma unroll
      for (int e = 1; e < 8; e++) if (s[e] > s[i1]) i1 = e;
      int i2 = (i1 == 0) ? 1 : 0;
#pragma unroll
      for (int e = 0; e < 8; e++) if (e != i1 && s[e] > s[i2]) i2 = e;
      atomicAdd(&lds_top1[i1], 1);
      int r1 = atomicAdd(&lds_cnt[i1], 1);
      int r2 = atomicAdd(&lds_cnt[i2], 1);
      tk_e[lt][0] = i1; tk_r[lt][0] = r1; tk_w[lt][0] = s[i1];
      tk_e[lt][1] = i2; tk_r[lt][1] = r2; tk_w[lt][1] = s[i2];
    }
  }
  if (lane == 0) {
#pragma unroll
    for (int e = 0; e < 8; e++) lds_ssum[wave][e] = ssum_local[e];
  }
  __syncthreads();
  if (tid < 8) {
    base[tid] = atomicAdd(&counts[tid], lds_cnt[tid]);
    atomicAdd(&top1cnt[tid], lds_top1[tid]);
    atomicAdd(&ssum[tid],
              lds_ssum[0][tid] + lds_ssum[1][tid] + lds_ssum[2][tid] + lds_ssum[3][tid]);
  }
  __syncthreads();
  if (tid < GB_TOK * 2) {
    int lt = tid >> 1, k = tid & 1;
    int e = tk_e[lt][k];
    int pos = base[e] + tk_r[lt][k];
    tok_list[e * T_TOK + pos] = blockIdx.x * GB_TOK + lt;
    wgt_list[e * T_TOK + pos] = tk_w[lt][k];
  }
}

// ---------------- scan + l_aux ----------------
__global__ void scan_kernel(const int* counts, const int* top1cnt, const float* ssum,
                            int* h_off, float* laux_out) {
  if (threadIdx.x == 0 && blockIdx.x == 0) {
    int off = 0;
    float l = 0.f;
    for (int e = 0; e < 8; e++) {
      h_off[e] = off;
      off += counts[e];
      l += (ssum[e] / (float)T_TOK) * ((float)top1cnt[e] / (float)T_TOK);
    }
    *laux_out = l * (float)NE;
  }
}

// ---------------- grouped GEMM: C = gatherA(M x K) * B^T-layout(N x K) ----------------
// MODE 0: A = x_bf gathered via tok_list; epilogue relu(acc + b1) -> h_buf bf16 (stride N==HID)
// MODE 1: A = h_buf rows (h_off[e]+row);   epilogue atomicAdd(out[tok], w*(acc + b2))
template <int MODE>
__global__ __launch_bounds__(256, 2) void moe_gemm_kernel(
    const unsigned short* __restrict__ A_src, const unsigned short* __restrict__ B_src,
    const float* __restrict__ bias, const int* __restrict__ counts,
    const int* __restrict__ h_off, const int* __restrict__ tok_list,
    const float* __restrict__ wgt_list, unsigned short* __restrict__ h_out,
    float* __restrict__ out, int N, int K) {
  __shared__ unsigned short s_a[BM][LDK];
  __shared__ unsigned short s_b[BN][LDK];

  const int e = blockIdx.z;
  const int n_e = counts[e];
  const int m0 = blockIdx.y * BM;
  if (m0 >= n_e) return;
  const int n0 = blockIdx.x * BN;
  const int tid = threadIdx.x;

  // staging assignments: chunk = it*256+tid; row = chunk>>3 (0..127), kc = tid&7
  const int kc = tid & 7;
  const unsigned short* a_ptr[4];
  const unsigned short* b_ptr[4];
  bool a_ok[4];
#pragma unroll
  for (int it = 0; it < 4; it++) {
    int row = it * 32 + (tid >> 3);
    int gr = m0 + row;
    a_ok[it] = (gr < n_e);
    int safe = a_ok[it] ? gr : 0;
    if (MODE == 0) {
      int tok = tok_list[e * T_TOK + safe];
      a_ptr[it] = A_src + (size_t)tok * K;
    } else {
      a_ptr[it] = A_src + (size_t)(h_off[e] + safe) * K;
    }
    b_ptr[it] = B_src + ((size_t)e * N + n0 + row) * K;
  }

  const int lane = tid & 63;
  const int wv = tid >> 6;
  const int wm = (wv >> 1) * 64;
  const int wn = (wv & 1) * 64;
  const int lm = lane & 15;
  const int quad = lane >> 4;

  floatx4 acc[4][4];
#pragma unroll
  for (int mi = 0; mi < 4; mi++)
#pragma unroll
    for (int ni = 0; ni < 4; ni++) acc[mi][ni] = (floatx4){0.f, 0.f, 0.f, 0.f};

  for (int kt = 0; kt < K; kt += BK) {
#pragma unroll
    for (int it = 0; it < 4; it++) {
      int row = it * 32 + (tid >> 3);
      uint4 va = {0u, 0u, 0u, 0u};
      if (a_ok[it]) va = *reinterpret_cast<const uint4*>(a_ptr[it] + kt + kc * 8);
      *reinterpret_cast<uint4*>(&s_a[row][kc * 8]) = va;
      uint4 vb = *reinterpret_cast<const uint4*>(b_ptr[it] + kt + kc * 8);
      *reinterpret_cast<uint4*>(&s_b[row][kc * 8]) = vb;
    }
    __syncthreads();
#pragma unroll
    for (int kk = 0; kk < 2; kk++) {
      shortx8 af[4], bfr[4];
#pragma unroll
      for (int mi = 0; mi < 4; mi++)
        af[mi] = *reinterpret_cast<const shortx8*>(&s_a[wm + mi * 16 + lm][kk * 32 + quad * 8]);
#pragma unroll
      for (int ni = 0; ni < 4; ni++)
        bfr[ni] = *reinterpret_cast<const shortx8*>(&s_b[wn + ni * 16 + lm][kk * 32 + quad * 8]);
#pragma unroll
      for (int mi = 0; mi < 4; mi++)
#pragma unroll
        for (int ni = 0; ni < 4; ni++)
          acc[mi][ni] = __builtin_amdgcn_mfma_f32_16x16x32_bf16(af[mi], bfr[ni], acc[mi][ni], 0, 0, 0);
    }
    __syncthreads();
  }

  // epilogue: D row = quad*4 + r, col = lm (verified C/D layout)
#pragma unroll
  for (int mi = 0; mi < 4; mi++) {
#pragma unroll
    for (int r = 0; r < 4; r++) {
      int row = m0 + wm + mi * 16 + quad * 4 + r;
      if (row >= n_e) continue;
      if (MODE == 0) {
        size_t base = (size_t)(h_off[e] + row) * N;
#pragma unroll
        for (int ni = 0; ni < 4; ni++) {
          int col = n0 + wn + ni * 16 + lm;
          float v = acc[mi][ni][r] + bias[e * N + col];
          v = fmaxf(v, 0.f);
          h_out[base + col] = f2bf(v);
        }
      } else {
        int tok = tok_list[e * T_TOK + row];
        float wgt = wgt_list[e * T_TOK + row];
        size_t base = (size_t)tok * N;
#pragma unroll
        for (int ni = 0; ni < 4; ni++) {
          int col = n0 + wn + ni * 16 + lm;
          float v = wgt * (acc[mi][ni][r] + bias[e * N + col]);
          atomicAdd(&out[base + col], v);
        }
      }
    }
  }
}

extern "C" void kernel_launch(void* const* d_in, const int* in_sizes, int n_in,
                              void* d_out, int out_size, void* d_ws, size_t ws_size,
                              hipStream_t stream) {
  const float* x  = (const float*)d_in[0];
  const float* wg = (const float*)d_in[1];
  const float* w1 = (const float*)d_in[2];
  const float* b1 = (const float*)d_in[3];
  const float* w2 = (const float*)d_in[4];
  const float* b2 = (const float*)d_in[5];
  float* out = (float*)d_out;

  char* ws = (char*)d_ws;
  // ws layout (bytes), all 256-aligned; total ~151.5 MB
  int*            counts   = (int*)(ws + 0);
  int*            top1cnt  = (int*)(ws + 32);
  float*          ssum     = (float*)(ws + 64);
  int*            h_off    = (int*)(ws + 96);
  int*            tok_list = (int*)(ws + 256);
  float*          wgt_list = (float*)(ws + 262400);
  unsigned short* x_bf     = (unsigned short*)(ws + 524544);
  unsigned short* w1t      = (unsigned short*)(ws + 17301760);
  unsigned short* w2t      = (unsigned short*)(ws + 50856192);
  unsigned short* h_buf    = (unsigned short*)(ws + 84410624);

  hipMemsetAsync(ws, 0, 256, stream);
  hipMemsetAsync(d_out, 0, (size_t)out_size * sizeof(float), stream);

  cast_x_kernel<<<(T_TOK * DIM) / 1024, 256, 0, stream>>>(x, x_bf);

  dim3 tb(32, 8);
  transpose_cast_kernel<<<dim3(HID / 32, DIM / 32, NE), tb, 0, stream>>>(w1, w1t, DIM, HID);
  transpose_cast_kernel<<<dim3(DIM / 32, HID / 32, NE), tb, 0, stream>>>(w2, w2t, HID, DIM);

  gate_kernel<<<T_TOK / GB_TOK, 256, 0, stream>>>(x, wg, counts, top1cnt, ssum, tok_list, wgt_list);
  scan_kernel<<<1, 64, 0, stream>>>(counts, top1cnt, ssum, h_off, out + (size_t)T_TOK * DIM);

  // GEMM1: M=n_e, N=HID, K=DIM
  moe_gemm_kernel<0><<<dim3(HID / BN, T_TOK / BM, NE), 256, 0, stream>>>(
      x_bf, w1t, b1, counts, h_off, tok_list, wgt_list, h_buf, nullptr, HID, DIM);
  // GEMM2: M=n_e, N=DIM, K=HID
  moe_gemm_kernel<1><<<dim3(DIM / BN, T_TOK / BM, NE), 256, 0, stream>>>(
      h_buf, w2t, b2, counts, h_off, tok_list, wgt_list, nullptr, out, DIM, HID);
}

// Round 3
// 518.875 us; speedup vs baseline: 1.6397x; 1.1287x over previous
//
#include <hip/hip_runtime.h>
#include <stdint.h>

#define T_TOK 8192
#define DIM   1024
#define HID   2048
#define NE    8

#define BM 128
#define BN 128
#define BK 64

#define GB_TOK 32  // tokens per gate block

typedef float floatx4 __attribute__((ext_vector_type(4)));
typedef short shortx8 __attribute__((ext_vector_type(8)));

typedef __attribute__((address_space(3))) void       lds_void;
typedef const __attribute__((address_space(1))) void gbl_void;

__device__ __forceinline__ unsigned short f2bf(float f) {
  unsigned int u = __float_as_uint(f);
  unsigned int r = 0x7fffu + ((u >> 16) & 1u);
  return (unsigned short)((u + r) >> 16);
}

// ---------------- cast x f32 -> bf16 ----------------
__global__ __launch_bounds__(256) void cast_x_kernel(const float* __restrict__ x,
                                                     unsigned short* __restrict__ xb) {
  size_t i = ((size_t)blockIdx.x * 256 + threadIdx.x) * 4;
  float4 v = *reinterpret_cast<const float4*>(x + i);
  ushort4 o;
  o.x = f2bf(v.x); o.y = f2bf(v.y); o.z = f2bf(v.z); o.w = f2bf(v.w);
  *reinterpret_cast<ushort4*>(xb + i) = o;
}

// ------------- transpose+cast: in [R][C] f32 -> out [C][R] bf16, blockIdx.z = expert -------------
__global__ __launch_bounds__(256) void transpose_cast_kernel(const float* __restrict__ in,
                                                             unsigned short* __restrict__ out,
                                                             int R, int C) {
  __shared__ float tile[32][33];
  const size_t eoff = (size_t)blockIdx.z * R * C;
  const float* ip = in + eoff;
  unsigned short* op = out + eoff;
  int c0 = blockIdx.x * 32, r0 = blockIdx.y * 32;
  int tx = threadIdx.x, ty = threadIdx.y;
#pragma unroll
  for (int i = 0; i < 4; i++)
    tile[ty + i * 8][tx] = ip[(size_t)(r0 + ty + i * 8) * C + (c0 + tx)];
  __syncthreads();
#pragma unroll
  for (int i = 0; i < 4; i++)
    op[(size_t)(c0 + ty + i * 8) * R + (r0 + tx)] = f2bf(tile[tx][ty + i * 8]);
}

// ---------------- gating: 32 tokens/block, hierarchical binning ----------------
__global__ __launch_bounds__(256) void gate_kernel(const float* __restrict__ x,
                                                   const float* __restrict__ wg,
                                                   int* counts, int* top1cnt, float* ssum,
                                                   int* tok_list, float* wgt_list) {
  __shared__ int   lds_cnt[8];
  __shared__ int   lds_top1[8];
  __shared__ float lds_ssum[4][8];
  __shared__ int   tk_e[GB_TOK][2];
  __shared__ int   tk_r[GB_TOK][2];
  __shared__ float tk_w[GB_TOK][2];
  __shared__ int   base[8];

  const int tid = threadIdx.x;
  const int wave = tid >> 6;
  const int lane = tid & 63;

  if (tid < 8) { lds_cnt[tid] = 0; lds_top1[tid] = 0; }
  if (tid < 32) lds_ssum[tid >> 3][tid & 7] = 0.f;
  __syncthreads();

  float ssum_local[8];
#pragma unroll
  for (int e = 0; e < 8; e++) ssum_local[e] = 0.f;

  for (int it = 0; it < GB_TOK / 4; it++) {
    const int lt = it * 4 + wave;
    const int t = blockIdx.x * GB_TOK + lt;

    float acc[8];
#pragma unroll
    for (int e = 0; e < 8; e++) acc[e] = 0.f;
    const float* xr = x + (size_t)t * DIM;
#pragma unroll
    for (int i = 0; i < 16; i++) {
      int d = i * 64 + lane;
      float xv = xr[d];
      const float4* wr = reinterpret_cast<const float4*>(wg + d * 8);
      float4 w0 = wr[0], w1 = wr[1];
      acc[0] += xv * w0.x; acc[1] += xv * w0.y; acc[2] += xv * w0.z; acc[3] += xv * w0.w;
      acc[4] += xv * w1.x; acc[5] += xv * w1.y; acc[6] += xv * w1.z; acc[7] += xv * w1.w;
    }
#pragma unroll
    for (int e = 0; e < 8; e++) {
#pragma unroll
      for (int off = 32; off > 0; off >>= 1) acc[e] += __shfl_xor(acc[e], off, 64);
    }
    if (lane == 0) {
      float mx = acc[0];
#pragma unroll
      for (int e = 1; e < 8; e++) mx = fmaxf(mx, acc[e]);
      float s[8], sum = 0.f;
#pragma unroll
      for (int e = 0; e < 8; e++) { s[e] = expf(acc[e] - mx); sum += s[e]; }
      float inv = 1.f / sum;
#pragma unroll
      for (int e = 0; e < 8; e++) { s[e] *= inv; ssum_local[e] += s[e]; }
      // top-2 (strict > : ties -> lower index, matches lax.top_k)
      int i1 = 0;
#pragma unroll
      for (int e = 1; e < 8; e++) if (s[e] > s[i1]) i1 = e;
      int i2 = (i1 == 0) ? 1 : 0;
#pragma unroll
      for (int e = 0; e < 8; e++) if (e != i1 && s[e] > s[i2]) i2 = e;
      atomicAdd(&lds_top1[i1], 1);
      int r1 = atomicAdd(&lds_cnt[i1], 1);
      int r2 = atomicAdd(&lds_cnt[i2], 1);
      tk_e[lt][0] = i1; tk_r[lt][0] = r1; tk_w[lt][0] = s[i1];
      tk_e[lt][1] = i2; tk_r[lt][1] = r2; tk_w[lt][1] = s[i2];
    }
  }
  if (lane == 0) {
#pragma unroll
    for (int e = 0; e < 8; e++) lds_ssum[wave][e] = ssum_local[e];
  }
  __syncthreads();
  if (tid < 8) {
    base[tid] = atomicAdd(&counts[tid], lds_cnt[tid]);
    atomicAdd(&top1cnt[tid], lds_top1[tid]);
    atomicAdd(&ssum[tid],
              lds_ssum[0][tid] + lds_ssum[1][tid] + lds_ssum[2][tid] + lds_ssum[3][tid]);
  }
  __syncthreads();
  if (tid < GB_TOK * 2) {
    int lt = tid >> 1, k = tid & 1;
    int e = tk_e[lt][k];
    int pos = base[e] + tk_r[lt][k];
    tok_list[e * T_TOK + pos] = blockIdx.x * GB_TOK + lt;
    wgt_list[e * T_TOK + pos] = tk_w[lt][k];
  }
}

// ---------------- scan + l_aux ----------------
__global__ void scan_kernel(const int* counts, const int* top1cnt, const float* ssum,
                            int* h_off, float* laux_out) {
  if (threadIdx.x == 0 && blockIdx.x == 0) {
    int off = 0;
    float l = 0.f;
    for (int e = 0; e < 8; e++) {
      h_off[e] = off;
      off += counts[e];
      l += (ssum[e] / (float)T_TOK) * ((float)top1cnt[e] / (float)T_TOK);
    }
    *laux_out = l * (float)NE;
  }
}

// ---------------- grouped GEMM: C = gatherA(M x K) * B^T-layout(N x K) ----------------
// m97-style staging: global_load_lds width=16, unpadded contiguous LDS.
// MODE 0: A = x_bf gathered via tok_list; epilogue relu(acc + b1) -> h_buf bf16 (stride N==HID)
// MODE 1: A = h_buf rows (h_off[e]+row);   epilogue atomicAdd(out[tok], w*(acc + b2))
template <int MODE>
__global__ __launch_bounds__(256, 2) void moe_gemm_kernel(
    const unsigned short* __restrict__ A_src, const unsigned short* __restrict__ B_src,
    const float* __restrict__ bias, const int* __restrict__ counts,
    const int* __restrict__ h_off, const int* __restrict__ tok_list,
    const float* __restrict__ wgt_list, unsigned short* __restrict__ h_out,
    float* __restrict__ out, int N, int K) {
  __shared__ unsigned short s_a[BM][BK];   // 16 KB, unpadded (global_load_lds layout)
  __shared__ unsigned short s_b[BN][BK];   // 16 KB

  const int e = blockIdx.z;
  const int n_e = counts[e];
  const int m0 = blockIdx.y * BM;
  if (m0 >= n_e) return;
  const int n0 = blockIdx.x * BN;
  const int tid = threadIdx.x;

  const int lane = tid & 63;
  const int wv = tid >> 6;
  const int lrow = lane >> 3;   // 0..7  (row within 8-row DMA call)
  const int lchk = lane & 7;    // 0..7  (16B chunk within 128B row)

  // per-lane global source pointers + wave-uniform LDS dests, 4 calls each for A and B
  const unsigned short* a_g[4];
  const unsigned short* b_g[4];
  lds_void* a_l[4];
  lds_void* b_l[4];
#pragma unroll
  for (int c = 0; c < 4; c++) {
    int ra = wv * 32 + c * 8 + lrow;              // tile row 0..127
    int gr = m0 + ra;
    int safe = (gr < n_e) ? gr : (n_e - 1);       // clamp: garbage only feeds discarded C rows
    const unsigned short* abase;
    if (MODE == 0) {
      int tok = tok_list[e * T_TOK + safe];
      abase = A_src + (size_t)tok * K;
    } else {
      abase = A_src + (size_t)(h_off[e] + safe) * K;
    }
    a_g[c] = abase + lchk * 8;
    b_g[c] = B_src + ((size_t)e * N + n0 + ra) * K + lchk * 8;
    a_l[c] = (lds_void*)&s_a[wv * 32 + c * 8][0];
    b_l[c] = (lds_void*)&s_b[wv * 32 + c * 8][0];
  }

  const int lm = lane & 15;
  const int quad = lane >> 4;
  const int wm = (wv >> 1) * 64;
  const int wn = (wv & 1) * 64;

  floatx4 acc[4][4];
#pragma unroll
  for (int mi = 0; mi < 4; mi++)
#pragma unroll
    for (int ni = 0; ni < 4; ni++) acc[mi][ni] = (floatx4){0.f, 0.f, 0.f, 0.f};

  for (int kt = 0; kt < K; kt += BK) {
#pragma unroll
    for (int c = 0; c < 4; c++) {
      __builtin_amdgcn_global_load_lds((gbl_void*)(a_g[c] + kt), a_l[c], 16, 0, 0);
      __builtin_amdgcn_global_load_lds((gbl_void*)(b_g[c] + kt), b_l[c], 16, 0, 0);
    }
    __syncthreads();
#pragma unroll
    for (int kk = 0; kk < 2; kk++) {
      shortx8 af[4], bfr[4];
#pragma unroll
      for (int mi = 0; mi < 4; mi++)
        af[mi] = *reinterpret_cast<const shortx8*>(&s_a[wm + mi * 16 + lm][kk * 32 + quad * 8]);
#pragma unroll
      for (int ni = 0; ni < 4; ni++)
        bfr[ni] = *reinterpret_cast<const shortx8*>(&s_b[wn + ni * 16 + lm][kk * 32 + quad * 8]);
#pragma unroll
      for (int mi = 0; mi < 4; mi++)
#pragma unroll
        for (int ni = 0; ni < 4; ni++)
          acc[mi][ni] = __builtin_amdgcn_mfma_f32_16x16x32_bf16(af[mi], bfr[ni], acc[mi][ni], 0, 0, 0);
    }
    __syncthreads();
  }

  // epilogue: D row = quad*4 + r, col = lm (verified C/D layout)
#pragma unroll
  for (int mi = 0; mi < 4; mi++) {
#pragma unroll
    for (int r = 0; r < 4; r++) {
      int row = m0 + wm + mi * 16 + quad * 4 + r;
      if (row >= n_e) continue;
      if (MODE == 0) {
        size_t base = (size_t)(h_off[e] + row) * N;
#pragma unroll
        for (int ni = 0; ni < 4; ni++) {
          int col = n0 + wn + ni * 16 + lm;
          float v = acc[mi][ni][r] + bias[e * N + col];
          v = fmaxf(v, 0.f);
          h_out[base + col] = f2bf(v);
        }
      } else {
        int tok = tok_list[e * T_TOK + row];
        float wgt = wgt_list[e * T_TOK + row];
        size_t base = (size_t)tok * N;
#pragma unroll
        for (int ni = 0; ni < 4; ni++) {
          int col = n0 + wn + ni * 16 + lm;
          float v = wgt * (acc[mi][ni][r] + bias[e * N + col]);
          atomicAdd(&out[base + col], v);
        }
      }
    }
  }
}

extern "C" void kernel_launch(void* const* d_in, const int* in_sizes, int n_in,
                              void* d_out, int out_size, void* d_ws, size_t ws_size,
                              hipStream_t stream) {
  const float* x  = (const float*)d_in[0];
  const float* wg = (const float*)d_in[1];
  const float* w1 = (const float*)d_in[2];
  const float* b1 = (const float*)d_in[3];
  const float* w2 = (const float*)d_in[4];
  const float* b2 = (const float*)d_in[5];
  float* out = (float*)d_out;

  char* ws = (char*)d_ws;
  // ws layout (bytes), all 256-aligned; total ~151.5 MB
  int*            counts   = (int*)(ws + 0);
  int*            top1cnt  = (int*)(ws + 32);
  float*          ssum     = (float*)(ws + 64);
  int*            h_off    = (int*)(ws + 96);
  int*            tok_list = (int*)(ws + 256);
  float*          wgt_list = (float*)(ws + 262400);
  unsigned short* x_bf     = (unsigned short*)(ws + 524544);
  unsigned short* w1t      = (unsigned short*)(ws + 17301760);
  unsigned short* w2t      = (unsigned short*)(ws + 50856192);
  unsigned short* h_buf    = (unsigned short*)(ws + 84410624);

  hipMemsetAsync(ws, 0, 256, stream);
  hipMemsetAsync(d_out, 0, (size_t)out_size * sizeof(float), stream);

  cast_x_kernel<<<(T_TOK * DIM) / 1024, 256, 0, stream>>>(x, x_bf);

  dim3 tb(32, 8);
  transpose_cast_kernel<<<dim3(HID / 32, DIM / 32, NE), tb, 0, stream>>>(w1, w1t, DIM, HID);
  transpose_cast_kernel<<<dim3(DIM / 32, HID / 32, NE), tb, 0, stream>>>(w2, w2t, HID, DIM);

  gate_kernel<<<T_TOK / GB_TOK, 256, 0, stream>>>(x, wg, counts, top1cnt, ssum, tok_list, wgt_list);
  scan_kernel<<<1, 64, 0, stream>>>(counts, top1cnt, ssum, h_off, out + (size_t)T_TOK * DIM);

  // GEMM1: M=n_e, N=HID, K=DIM
  moe_gemm_kernel<0><<<dim3(HID / BN, T_TOK / BM, NE), 256, 0, stream>>>(
      x_bf, w1t, b1, counts, h_off, tok_list, wgt_list, h_buf, nullptr, HID, DIM);
  // GEMM2: M=n_e, N=DIM, K=HID
  moe_gemm_kernel<1><<<dim3(DIM / BN, T_TOK / BM, NE), 256, 0, stream>>>(
      h_buf, w2t, b2, counts, h_off, tok_list, wgt_list, nullptr, out, DIM, HID);
}

// Round 4
// 490.732 us; speedup vs baseline: 1.7337x; 1.0573x over previous
//
#include <hip/hip_runtime.h>
#include <stdint.h>

#define T_TOK 8192
#define DIM   1024
#define HID   2048
#define NE    8

#define BM 128
#define BN 128
#define BK 64

#define GB_TOK 32  // tokens per gate block

typedef float floatx4 __attribute__((ext_vector_type(4)));
typedef short shortx8 __attribute__((ext_vector_type(8)));

typedef __attribute__((address_space(3))) void       lds_void;
typedef const __attribute__((address_space(1))) void gbl_void;

__device__ __forceinline__ unsigned short f2bf(float f) {
  unsigned int u = __float_as_uint(f);
  unsigned int r = 0x7fffu + ((u >> 16) & 1u);
  return (unsigned short)((u + r) >> 16);
}

// ---------------- cast x f32 -> bf16 ----------------
__global__ __launch_bounds__(256) void cast_x_kernel(const float* __restrict__ x,
                                                     unsigned short* __restrict__ xb) {
  size_t i = ((size_t)blockIdx.x * 256 + threadIdx.x) * 4;
  float4 v = *reinterpret_cast<const float4*>(x + i);
  ushort4 o;
  o.x = f2bf(v.x); o.y = f2bf(v.y); o.z = f2bf(v.z); o.w = f2bf(v.w);
  *reinterpret_cast<ushort4*>(xb + i) = o;
}

// ------------- transpose+cast: in [R][C] f32 -> out [C][R] bf16, blockIdx.z = expert -------------
__global__ __launch_bounds__(256) void transpose_cast_kernel(const float* __restrict__ in,
                                                             unsigned short* __restrict__ out,
                                                             int R, int C) {
  __shared__ float tile[32][33];
  const size_t eoff = (size_t)blockIdx.z * R * C;
  const float* ip = in + eoff;
  unsigned short* op = out + eoff;
  int c0 = blockIdx.x * 32, r0 = blockIdx.y * 32;
  int tx = threadIdx.x, ty = threadIdx.y;
#pragma unroll
  for (int i = 0; i < 4; i++)
    tile[ty + i * 8][tx] = ip[(size_t)(r0 + ty + i * 8) * C + (c0 + tx)];
  __syncthreads();
#pragma unroll
  for (int i = 0; i < 4; i++)
    op[(size_t)(c0 + ty + i * 8) * R + (r0 + tx)] = f2bf(tile[tx][ty + i * 8]);
}

// ---------------- gating: 32 tokens/block, hierarchical binning ----------------
__global__ __launch_bounds__(256) void gate_kernel(const float* __restrict__ x,
                                                   const float* __restrict__ wg,
                                                   int* counts, int* top1cnt, float* ssum,
                                                   int* tok_list, float* wgt_list) {
  __shared__ int   lds_cnt[8];
  __shared__ int   lds_top1[8];
  __shared__ float lds_ssum[4][8];
  __shared__ int   tk_e[GB_TOK][2];
  __shared__ int   tk_r[GB_TOK][2];
  __shared__ float tk_w[GB_TOK][2];
  __shared__ int   base[8];

  const int tid = threadIdx.x;
  const int wave = tid >> 6;
  const int lane = tid & 63;

  if (tid < 8) { lds_cnt[tid] = 0; lds_top1[tid] = 0; }
  if (tid < 32) lds_ssum[tid >> 3][tid & 7] = 0.f;
  __syncthreads();

  float ssum_local[8];
#pragma unroll
  for (int e = 0; e < 8; e++) ssum_local[e] = 0.f;

  for (int it = 0; it < GB_TOK / 4; it++) {
    const int lt = it * 4 + wave;
    const int t = blockIdx.x * GB_TOK + lt;

    float acc[8];
#pragma unroll
    for (int e = 0; e < 8; e++) acc[e] = 0.f;
    const float* xr = x + (size_t)t * DIM;
#pragma unroll
    for (int i = 0; i < 16; i++) {
      int d = i * 64 + lane;
      float xv = xr[d];
      const float4* wr = reinterpret_cast<const float4*>(wg + d * 8);
      float4 w0 = wr[0], w1 = wr[1];
      acc[0] += xv * w0.x; acc[1] += xv * w0.y; acc[2] += xv * w0.z; acc[3] += xv * w0.w;
      acc[4] += xv * w1.x; acc[5] += xv * w1.y; acc[6] += xv * w1.z; acc[7] += xv * w1.w;
    }
#pragma unroll
    for (int e = 0; e < 8; e++) {
#pragma unroll
      for (int off = 32; off > 0; off >>= 1) acc[e] += __shfl_xor(acc[e], off, 64);
    }
    if (lane == 0) {
      float mx = acc[0];
#pragma unroll
      for (int e = 1; e < 8; e++) mx = fmaxf(mx, acc[e]);
      float s[8], sum = 0.f;
#pragma unroll
      for (int e = 0; e < 8; e++) { s[e] = expf(acc[e] - mx); sum += s[e]; }
      float inv = 1.f / sum;
#pragma unroll
      for (int e = 0; e < 8; e++) { s[e] *= inv; ssum_local[e] += s[e]; }
      // top-2 (strict > : ties -> lower index, matches lax.top_k)
      int i1 = 0;
#pragma unroll
      for (int e = 1; e < 8; e++) if (s[e] > s[i1]) i1 = e;
      int i2 = (i1 == 0) ? 1 : 0;
#pragma unroll
      for (int e = 0; e < 8; e++) if (e != i1 && s[e] > s[i2]) i2 = e;
      atomicAdd(&lds_top1[i1], 1);
      int r1 = atomicAdd(&lds_cnt[i1], 1);
      int r2 = atomicAdd(&lds_cnt[i2], 1);
      tk_e[lt][0] = i1; tk_r[lt][0] = r1; tk_w[lt][0] = s[i1];
      tk_e[lt][1] = i2; tk_r[lt][1] = r2; tk_w[lt][1] = s[i2];
    }
  }
  if (lane == 0) {
#pragma unroll
    for (int e = 0; e < 8; e++) lds_ssum[wave][e] = ssum_local[e];
  }
  __syncthreads();
  if (tid < 8) {
    base[tid] = atomicAdd(&counts[tid], lds_cnt[tid]);
    atomicAdd(&top1cnt[tid], lds_top1[tid]);
    atomicAdd(&ssum[tid],
              lds_ssum[0][tid] + lds_ssum[1][tid] + lds_ssum[2][tid] + lds_ssum[3][tid]);
  }
  __syncthreads();
  if (tid < GB_TOK * 2) {
    int lt = tid >> 1, k = tid & 1;
    int e = tk_e[lt][k];
    int pos = base[e] + tk_r[lt][k];
    tok_list[e * T_TOK + pos] = blockIdx.x * GB_TOK + lt;
    wgt_list[e * T_TOK + pos] = tk_w[lt][k];
  }
}

// ---------------- scan + l_aux ----------------
__global__ void scan_kernel(const int* counts, const int* top1cnt, const float* ssum,
                            int* h_off, float* laux_out) {
  if (threadIdx.x == 0 && blockIdx.x == 0) {
    int off = 0;
    float l = 0.f;
    for (int e = 0; e < 8; e++) {
      h_off[e] = off;
      off += counts[e];
      l += (ssum[e] / (float)T_TOK) * ((float)top1cnt[e] / (float)T_TOK);
    }
    *laux_out = l * (float)NE;
  }
}

// ---------------- grouped GEMM: C = gatherA(M x K) * B^T-layout(N x K) ----------------
// global_load_lds width=16 staging with XOR-swizzled chunk placement:
//   LDS row r, physical 16B-chunk c holds global chunk (c ^ (r&7)).
//   -> read-side ds_read_b128 spreads quads across all 32 banks (2-way max, free).
// MODE 0: A = x_bf gathered via tok_list; epilogue relu(acc + b1) -> h_buf bf16 (stride N==HID)
// MODE 1: A = h_buf rows (h_off[e]+row);   epilogue atomicAdd(out[tok], w*(acc + b2))
template <int MODE>
__global__ __launch_bounds__(256, 4) void moe_gemm_kernel(
    const unsigned short* __restrict__ A_src, const unsigned short* __restrict__ B_src,
    const float* __restrict__ bias, const int* __restrict__ counts,
    const int* __restrict__ h_off, const int* __restrict__ tok_list,
    const float* __restrict__ wgt_list, unsigned short* __restrict__ h_out,
    float* __restrict__ out, int N, int K) {
  __shared__ unsigned short s_a[BM][BK];   // 16 KB, unpadded (global_load_lds layout)
  __shared__ unsigned short s_b[BN][BK];   // 16 KB

  const int e = blockIdx.z;
  const int n_e = counts[e];
  const int m0 = blockIdx.y * BM;
  if (m0 >= n_e) return;
  const int n0 = blockIdx.x * BN;
  const int tid = threadIdx.x;

  const int lane = tid & 63;
  const int wv = tid >> 6;
  const int lrow = lane >> 3;            // 0..7  (row within 8-row DMA call)
  const int lchk = (lane & 7) ^ lrow;    // XOR-swizzled global 16B chunk index

  // per-lane global source pointers + wave-uniform LDS dests, 4 calls each for A and B
  const unsigned short* a_g[4];
  const unsigned short* b_g[4];
  lds_void* a_l[4];
  lds_void* b_l[4];
#pragma unroll
  for (int c = 0; c < 4; c++) {
    int ra = wv * 32 + c * 8 + lrow;              // tile row 0..127
    int gr = m0 + ra;
    int safe = (gr < n_e) ? gr : (n_e - 1);       // clamp: garbage only feeds discarded C rows
    const unsigned short* abase;
    if (MODE == 0) {
      int tok = tok_list[e * T_TOK + safe];
      abase = A_src + (size_t)tok * K;
    } else {
      abase = A_src + (size_t)(h_off[e] + safe) * K;
    }
    a_g[c] = abase + lchk * 8;
    b_g[c] = B_src + ((size_t)e * N + n0 + ra) * K + lchk * 8;
    a_l[c] = (lds_void*)&s_a[wv * 32 + c * 8][0];
    b_l[c] = (lds_void*)&s_b[wv * 32 + c * 8][0];
  }

  const int lm = lane & 15;
  const int quad = lane >> 4;
  const int r7 = lm & 7;                 // == row&7 for all fragment rows
  const int wm = (wv >> 1) * 64;
  const int wn = (wv & 1) * 64;

  floatx4 acc[4][4];
#pragma unroll
  for (int mi = 0; mi < 4; mi++)
#pragma unroll
    for (int ni = 0; ni < 4; ni++) acc[mi][ni] = (floatx4){0.f, 0.f, 0.f, 0.f};

  for (int kt = 0; kt < K; kt += BK) {
#pragma unroll
    for (int c = 0; c < 4; c++) {
      __builtin_amdgcn_global_load_lds((gbl_void*)(a_g[c] + kt), a_l[c], 16, 0, 0);
      __builtin_amdgcn_global_load_lds((gbl_void*)(b_g[c] + kt), b_l[c], 16, 0, 0);
    }
    __syncthreads();
#pragma unroll
    for (int kk = 0; kk < 2; kk++) {
      const int pc = ((kk << 2) + quad) ^ r7;   // physical chunk for this lane's fragment
      shortx8 af[4], bfr[4];
#pragma unroll
      for (int mi = 0; mi < 4; mi++)
        af[mi] = *reinterpret_cast<const shortx8*>(&s_a[wm + mi * 16 + lm][pc << 3]);
#pragma unroll
      for (int ni = 0; ni < 4; ni++)
        bfr[ni] = *reinterpret_cast<const shortx8*>(&s_b[wn + ni * 16 + lm][pc << 3]);
#pragma unroll
      for (int mi = 0; mi < 4; mi++)
#pragma unroll
        for (int ni = 0; ni < 4; ni++)
          acc[mi][ni] = __builtin_amdgcn_mfma_f32_16x16x32_bf16(af[mi], bfr[ni], acc[mi][ni], 0, 0, 0);
    }
    __syncthreads();
  }

  // epilogue: D row = quad*4 + r, col = lm (verified C/D layout)
#pragma unroll
  for (int mi = 0; mi < 4; mi++) {
#pragma unroll
    for (int r = 0; r < 4; r++) {
      int row = m0 + wm + mi * 16 + quad * 4 + r;
      if (row >= n_e) continue;
      if (MODE == 0) {
        size_t base = (size_t)(h_off[e] + row) * N;
#pragma unroll
        for (int ni = 0; ni < 4; ni++) {
          int col = n0 + wn + ni * 16 + lm;
          float v = acc[mi][ni][r] + bias[e * N + col];
          v = fmaxf(v, 0.f);
          h_out[base + col] = f2bf(v);
        }
      } else {
        int tok = tok_list[e * T_TOK + row];
        float wgt = wgt_list[e * T_TOK + row];
        size_t base = (size_t)tok * N;
#pragma unroll
        for (int ni = 0; ni < 4; ni++) {
          int col = n0 + wn + ni * 16 + lm;
          float v = wgt * (acc[mi][ni][r] + bias[e * N + col]);
          atomicAdd(&out[base + col], v);
        }
      }
    }
  }
}

extern "C" void kernel_launch(void* const* d_in, const int* in_sizes, int n_in,
                              void* d_out, int out_size, void* d_ws, size_t ws_size,
                              hipStream_t stream) {
  const float* x  = (const float*)d_in[0];
  const float* wg = (const float*)d_in[1];
  const float* w1 = (const float*)d_in[2];
  const float* b1 = (const float*)d_in[3];
  const float* w2 = (const float*)d_in[4];
  const float* b2 = (const float*)d_in[5];
  float* out = (float*)d_out;

  char* ws = (char*)d_ws;
  // ws layout (bytes), all 256-aligned; total ~151.5 MB
  int*            counts   = (int*)(ws + 0);
  int*            top1cnt  = (int*)(ws + 32);
  float*          ssum     = (float*)(ws + 64);
  int*            h_off    = (int*)(ws + 96);
  int*            tok_list = (int*)(ws + 256);
  float*          wgt_list = (float*)(ws + 262400);
  unsigned short* x_bf     = (unsigned short*)(ws + 524544);
  unsigned short* w1t      = (unsigned short*)(ws + 17301760);
  unsigned short* w2t      = (unsigned short*)(ws + 50856192);
  unsigned short* h_buf    = (unsigned short*)(ws + 84410624);

  hipMemsetAsync(ws, 0, 256, stream);
  hipMemsetAsync(d_out, 0, (size_t)out_size * sizeof(float), stream);

  cast_x_kernel<<<(T_TOK * DIM) / 1024, 256, 0, stream>>>(x, x_bf);

  dim3 tb(32, 8);
  transpose_cast_kernel<<<dim3(HID / 32, DIM / 32, NE), tb, 0, stream>>>(w1, w1t, DIM, HID);
  transpose_cast_kernel<<<dim3(DIM / 32, HID / 32, NE), tb, 0, stream>>>(w2, w2t, HID, DIM);

  gate_kernel<<<T_TOK / GB_TOK, 256, 0, stream>>>(x, wg, counts, top1cnt, ssum, tok_list, wgt_list);
  scan_kernel<<<1, 64, 0, stream>>>(counts, top1cnt, ssum, h_off, out + (size_t)T_TOK * DIM);

  // GEMM1: M=n_e, N=HID, K=DIM
  moe_gemm_kernel<0><<<dim3(HID / BN, T_TOK / BM, NE), 256, 0, stream>>>(
      x_bf, w1t, b1, counts, h_off, tok_list, wgt_list, h_buf, nullptr, HID, DIM);
  // GEMM2: M=n_e, N=DIM, K=HID
  moe_gemm_kernel<1><<<dim3(DIM / BN, T_TOK / BM, NE), 256, 0, stream>>>(
      h_buf, w2t, b2, counts, h_off, tok_list, wgt_list, nullptr, out, DIM, HID);
}